// Round 17
// baseline (3803.841 us; speedup 1.0000x reference)
//
#include <hip/hip_runtime.h>
#include <hip/hip_bf16.h>
#include <cstdint>
#include <cstddef>

#define B_ALL 256
#define T_SZ  1024

typedef __attribute__((ext_vector_type(8))) _Float16  halfx8;
typedef __attribute__((ext_vector_type(4))) _Float16  halfx4;
typedef __attribute__((ext_vector_type(4))) float     f32x4;

__device__ __forceinline__ float sig_(float x) {
    return __builtin_amdgcn_rcpf(1.0f + __expf(-x));
}
__device__ __forceinline__ float tanh_(float x) {
    float ax = fabsf(x);
    float e  = __expf(-2.0f * ax);
    float t  = (1.0f - e) * __builtin_amdgcn_rcpf(1.0f + e);
    return copysignf(t, x);
}

// LDS-only barrier (no vmcnt drain; vmem deps get compiler vmcnt waits at use).
__device__ __forceinline__ void bar_lgkm() {
    asm volatile("s_waitcnt lgkmcnt(0)\n\ts_barrier" ::: "memory");
}

// ---------------- conv (causal, k=5) + relu -> X1[b_local][t][64] (fp16) ----------------
__global__ void conv_relu_kernel(const float* __restrict__ x, const float* __restrict__ w,
                                 const float* __restrict__ bias, _Float16* __restrict__ out,
                                 int bg0)
{
    int c  = threadIdx.x & 63;
    int tq = threadIdx.x >> 6;
    int t  = blockIdx.x * 4 + tq;
    int b  = blockIdx.y;
    const float* xb = x + (size_t)(bg0 + b) * T_SZ;
    float s = bias[c];
#pragma unroll
    for (int k = 0; k < 5; ++k) {
        int ti = t - 4 + k;
        float xv = (ti >= 0) ? xb[ti] : 0.0f;
        s = fmaf(w[c * 5 + k], xv, s);
    }
    out[((size_t)b * T_SZ + t) * 64 + c] = (_Float16)fmaxf(s, 0.0f);
}

// ---------------- fused: LSTM rec (chunk ci) + input-proj MFMA (chunk ci+1) ----------------
// 256-thread blocks, amdgpu_waves_per_eu(1,1): codegen targets 1 wave/EU and may use the
// full 512-VGPR budget -> rec's 2 hh-groups of register-resident W_hh (128 VGPRs at H=128)
// must NOT spill. Grid 256 = 1 block/CU -> rec CUs run 1 wave/SIMD; two independent
// MFMA->activation chains per wave fill the latency shadow. Proj: persistent 128x128 tiles.
template <int H, bool WRITE_Y>
__global__ __attribute__((amdgpu_flat_work_group_size(256, 256), amdgpu_waves_per_eu(1, 1)))
void fused_step(
    // rec
    const _Float16* __restrict__ xwR, const float* __restrict__ w_hh,
    _Float16* __restrict__ y, float* __restrict__ lastOut,
    float* __restrict__ Hst, float* __restrict__ Cst,
    int Bg, int Tc, int lg, int step0, int zeroInit, int writeLast,
    int nRecBlocks, int ndirRec,
    // proj
    const _Float16* __restrict__ A, const float* __restrict__ W,
    const float* __restrict__ bias, _Float16* __restrict__ xwOut,
    int K, int N, int t0p, int MT, int NT, int nProjB, int totTiles)
{
    __shared__ __align__(16) char smem[32768];
    const int tid = threadIdx.x;
    const int w   = tid >> 6;
    const int l   = tid & 63;
    const int l15 = l & 15;
    const int q4  = l >> 4;

    if ((int)blockIdx.x < nRecBlocks) {
        // ================= REC =================
        constexpr int FH  = 4 * H;
        constexpr int KT  = H / 32;
        constexpr int NCH = H / 8;              // 16B chunks per h row
        constexpr int NHG = H / 64;             // hh-groups per lane (4 waves)
        int rb  = blockIdx.x;
        int dir = (ndirRec == 2) ? (rb & 1) : 0;
        int bt  = (ndirRec == 2) ? (rb >> 1) : rb;
        int brow = bt * 4 + q4;                 // this lane's batch row
        int hhg[NHG];
#pragma unroll
        for (int hg = 0; hg < NHG; ++hg) hhg[hg] = (w + hg * 4) * 16 + l15;

        _Float16* hb = (_Float16*)smem;         // [parity][16 rows][NCH chunks] XOR-swizzled
        auto hAddr = [&](int p, int row, int ch) -> _Float16* {
            return hb + ((((p * 16 + row) * NCH) + (ch ^ (row & (NCH - 1)))) << 3);
        };
        for (int i = tid; i < 2 * 16 * H; i += 256) hb[i] = (_Float16)0.f;
        __syncthreads();                        // zero-init visible before h-init writes

        halfx8 wf[NHG][4][KT];
        float creg[NHG];
#pragma unroll
        for (int hg = 0; hg < NHG; ++hg) creg[hg] = 0.f;
        {
            const float* wbase = w_hh + (size_t)dir * FH * H;
#pragma unroll
            for (int hg = 0; hg < NHG; ++hg) {
#pragma unroll
                for (int gate = 0; gate < 4; ++gate) {
                    const float* wrow = wbase + (size_t)(gate * H + hhg[hg]) * H;
#pragma unroll
                    for (int kt = 0; kt < KT; ++kt) {
                        const float* src = wrow + kt * 32 + q4 * 8;
                        float4 a = *(const float4*)(src);
                        float4 b = *(const float4*)(src + 4);
                        halfx8 v;
                        v[0] = (_Float16)a.x; v[1] = (_Float16)a.y; v[2] = (_Float16)a.z; v[3] = (_Float16)a.w;
                        v[4] = (_Float16)b.x; v[5] = (_Float16)b.y; v[6] = (_Float16)b.z; v[7] = (_Float16)b.w;
                        wf[hg][gate][kt] = v;
                    }
                }
                float hv = 0.f;
                if (!zeroInit) {
                    hv       = Hst[((size_t)dir * Bg + brow) * H + hhg[hg]];
                    creg[hg] = Cst[((size_t)dir * Bg + brow) * H + hhg[hg]];
                }
                hAddr(0, q4 * 4, hhg[hg] >> 3)[hhg[hg] & 7] = (_Float16)hv;
            }
        }
        const _Float16* xbp[NHG];
#pragma unroll
        for (int hg = 0; hg < NHG; ++hg)
            xbp[hg] = xwR + (size_t)dir * Tc * Bg * FH + (size_t)brow * FH + hhg[hg] * 4;
        const size_t xstride = (size_t)Bg * FH;

        halfx4 pf[4][NHG];                      // constant-indexed only
#pragma unroll
        for (int j = 0; j < 4; ++j)
#pragma unroll
            for (int hg = 0; hg < NHG; ++hg)
                pf[j][hg] = *(const halfx4*)(xbp[hg] + (size_t)j * xstride);
        __syncthreads();

        // one sub-step: reads h parity P, writes 1-P; refill load issued BEFORE MFMAs.
        auto step = [&](int sl, int P, halfx4* xv, int refill) {
            const int t = dir ? (T_SZ - 1 - (step0 + sl)) : (step0 + sl);
            halfx4 nxt[NHG];
            if (refill) {
#pragma unroll
                for (int hg = 0; hg < NHG; ++hg)
                    nxt[hg] = *(const halfx4*)(xbp[hg] + (size_t)(sl + 4) * xstride);
            }
            halfx8 af[KT];
#pragma unroll
            for (int kt = 0; kt < KT; ++kt)
                af[kt] = *(const halfx8*)hAddr(P, l15, kt * 4 + q4);
#pragma unroll
            for (int hg = 0; hg < NHG; ++hg) {
                float g4[4];
#pragma unroll
                for (int gate = 0; gate < 4; ++gate) {
                    f32x4 a0 = {0.f, 0.f, 0.f, 0.f};
#pragma unroll
                    for (int kt = 0; kt < KT / 2; ++kt)
                        a0 = __builtin_amdgcn_mfma_f32_16x16x32_f16(af[kt], wf[hg][gate][kt], a0, 0, 0, 0);
                    if (KT > 1) {
                        f32x4 a1 = {0.f, 0.f, 0.f, 0.f};
#pragma unroll
                        for (int kt = KT / 2; kt < KT; ++kt)
                            a1 = __builtin_amdgcn_mfma_f32_16x16x32_f16(af[kt], wf[hg][gate][kt], a1, 0, 0, 0);
                        g4[gate] = a0[0] + a1[0] + (float)xv[hg][gate];
                    } else {
                        g4[gate] = a0[0] + (float)xv[hg][gate];
                    }
                }
                float iv = fminf(fmaxf(g4[0], -25.f), 25.f);
                float fv = fminf(fmaxf(g4[1], -25.f), 25.f);
                float gv = fminf(fmaxf(g4[2], -12.f), 12.f);
                float ov = fminf(fmaxf(g4[3], -25.f), 25.f);
                float Af = 1.f + __expf(-fv);
                float Bi = 1.f + __expf(-iv);
                float G  = __expf(2.f * gv);
                float Gp = G + 1.f, Gm = G - 1.f;
                float num = fmaf(creg[hg] * Bi, Gp, Af * Gm);
                float cn  = num * __builtin_amdgcn_rcpf(Af * Bi * Gp);
                creg[hg] = cn;
                float cc = fminf(fmaxf(cn, -25.f), 25.f);
                float E  = __expf(2.f * cc);
                float hv = (E - 1.f) * __builtin_amdgcn_rcpf((1.f + __expf(-ov)) * (E + 1.f));
                hAddr(1 - P, q4 * 4, hhg[hg] >> 3)[hhg[hg] & 7] = (_Float16)hv;
                if (WRITE_Y) {
                    y[((size_t)brow * T_SZ + t) * (2 * H) + dir * H + hhg[hg]] = (_Float16)hv;
                } else if (writeLast && sl == Tc - 1) {
                    lastOut[brow * 128 + hhg[hg]] = hv;
                }
                if (sl == Tc - 1) {
                    Hst[((size_t)dir * Bg + brow) * H + hhg[hg]] = hv;
                    Cst[((size_t)dir * Bg + brow) * H + hhg[hg]] = cn;
                }
            }
            if (refill) {
#pragma unroll
                for (int hg = 0; hg < NHG; ++hg) xv[hg] = nxt[hg];
            }
        };

        for (int sl4 = 0; sl4 < Tc; sl4 += 4) {
            step(sl4 + 0, 0, pf[0], sl4 + 4 < Tc);
            bar_lgkm();
            step(sl4 + 1, 1, pf[1], sl4 + 5 < Tc);
            bar_lgkm();
            step(sl4 + 2, 0, pf[2], sl4 + 6 < Tc);
            bar_lgkm();
            step(sl4 + 3, 1, pf[3], sl4 + 7 < Tc);
            bar_lgkm();
        }
    } else {
        // ================= PROJ (persistent 4-wave blocks, tile loop) =================
        const int Tcp = 1 << lg;
        const int H4  = N >> 2;
        int pb = blockIdx.x - nRecBlocks;

        for (int tile = pb; tile < totTiles; tile += nProjB) {
            int mi   = tile % MT;
            int rest = tile / MT;
            int ni   = rest % NT;
            int dirp = rest / NT;
            const float* Wd = W + (size_t)dirp * N * K;
            const float* bd = bias + (size_t)dirp * N;
            _Float16*    od = xwOut + (size_t)dirp * Tcp * Bg * N;

            _Float16 (*As)[40] = (_Float16(*)[40])smem;             // 128*40*2 = 10240
            _Float16 (*Ws)[40] = (_Float16(*)[40])(smem + 10240);   // 10240

            const int m0 = mi * 128;
            const int n0 = ni * 128;
            const int wm = (w & 1) * 64;
            const int wn = (w >> 1) * 64;

            f32x4 acc[4][4];
#pragma unroll
            for (int i = 0; i < 4; i++)
#pragma unroll
                for (int j = 0; j < 4; j++) acc[i][j] = (f32x4){0.f, 0.f, 0.f, 0.f};

            for (int k0 = 0; k0 < K; k0 += 32) {
#pragma unroll
                for (int pass = 0; pass < 2; ++pass) {  // stage A: 128 rows x 32 fp16
                    int c2  = tid + pass * 256;
                    int row = c2 >> 2;
                    int ko  = (c2 & 3) * 8;
                    int m   = m0 + row;
                    int bA  = m >> lg, tl = m & (Tcp - 1);
                    int t   = dirp ? (T_SZ - 1 - (t0p + tl)) : (t0p + tl);
                    const _Float16* src = A + ((size_t)bA * T_SZ + t) * K + k0 + ko;
                    *(halfx8*)&As[row][ko] = *(const halfx8*)src;
                }
#pragma unroll
                for (int pass = 0; pass < 4; ++pass) {  // stage W: 128 rows x 32 f32->f16
                    int c2  = tid + pass * 256;
                    int row = c2 >> 3;
                    int ko  = (c2 & 7) * 4;
                    int n_o = n0 + row;
                    int nr  = (n_o & 3) * H4 + (n_o >> 2);
                    float4 f = *(const float4*)&Wd[(size_t)nr * K + k0 + ko];
                    halfx4 v;
                    v[0] = (_Float16)f.x; v[1] = (_Float16)f.y; v[2] = (_Float16)f.z; v[3] = (_Float16)f.w;
                    *(halfx4*)&Ws[row][ko] = v;
                }
                bar_lgkm();
                halfx8 af[4], bfr[4];
#pragma unroll
                for (int i = 0; i < 4; i++) af[i]  = *(const halfx8*)&As[wm + i * 16 + l15][q4 * 8];
#pragma unroll
                for (int j = 0; j < 4; j++) bfr[j] = *(const halfx8*)&Ws[wn + j * 16 + l15][q4 * 8];
#pragma unroll
                for (int i = 0; i < 4; i++)
#pragma unroll
                    for (int j = 0; j < 4; j++)
                        acc[i][j] = __builtin_amdgcn_mfma_f32_16x16x32_f16(af[i], bfr[j], acc[i][j], 0, 0, 0);
                bar_lgkm();
            }

            // epilogue: stage C in LDS [128][128] fp16, then coalesced stores
            _Float16 (*Ct)[128] = (_Float16(*)[128])smem;
#pragma unroll
            for (int i = 0; i < 4; i++) {
#pragma unroll
                for (int j = 0; j < 4; j++) {
                    int o_l = wn + j * 16 + l15;
                    int n_o = n0 + o_l;
                    float bi = bd[(n_o & 3) * H4 + (n_o >> 2)];
#pragma unroll
                    for (int r = 0; r < 4; r++)
                        Ct[wm + i * 16 + q4 * 4 + r][o_l] = (_Float16)(acc[i][j][r] + bi);
                }
            }
            bar_lgkm();
            {
                int row = tid >> 1;          // 0..127
                int seg = tid & 1;           // 0..1, 64 fp16 each
                int m   = m0 + row;
                int bO  = m >> lg, tl = m & (Tcp - 1);
                _Float16* dst = od + ((size_t)tl * Bg + bO) * N + n0 + seg * 64;
                const _Float16* srcp = &Ct[row][seg * 64];
#pragma unroll
                for (int u = 0; u < 8; ++u)
                    *(halfx8*)(dst + u * 8) = *(const halfx8*)(srcp + u * 8);
            }
            bar_lgkm();   // Ct reads done before next tile's staging overwrites smem
        }
    }
}

// ---------------- layer-3 backward: exactly one step from zero state ----------------
__global__ __launch_bounds__(256) void lstm3_bwd_kernel(
    const _Float16* __restrict__ y2, const float* __restrict__ w_ih3,
    const float* __restrict__ b3, float* __restrict__ H3)
{
    int b = blockIdx.x, g = threadIdx.x;
    __shared__ float xr[256];
    __shared__ float gsh[256];
    xr[g] = (float)y2[((size_t)b * T_SZ + (T_SZ - 1)) * 256 + g];
    __syncthreads();
    const float* wr = w_ih3 + (size_t)256 * 256 + (size_t)g * 256;  // dir 1
    float acc = b3[256 + g];
#pragma unroll 4
    for (int k = 0; k < 256; k++) acc = fmaf(wr[k], xr[k], acc);
    gsh[g] = acc;
    __syncthreads();
    if (g < 64) {
        float iv = gsh[g], gv = gsh[128 + g], ov = gsh[192 + g];
        float ct = sig_(iv) * tanh_(gv);   // c0 = 0 -> forget term vanishes
        float hv = sig_(ov) * tanh_(ct);
        H3[b * 128 + 64 + g] = hv;
    }
}

// ---------------- FC ----------------
__global__ void fc_kernel(const float* __restrict__ in, const float* __restrict__ W,
                          const float* __restrict__ bias, float* __restrict__ out,
                          int K, int N, int doRelu)
{
    int b = blockIdx.x;
    int g = threadIdx.x;
    extern __shared__ float xr[];
    for (int i = g; i < K; i += blockDim.x) xr[i] = in[(size_t)b * K + i];
    __syncthreads();
    if (g < N) {
        const float* wr = W + (size_t)g * K;
        float acc = bias[g];
        for (int k = 0; k < K; k++) acc = fmaf(wr[k], xr[k], acc);
        if (doRelu) acc = fmaxf(acc, 0.f);
        out[(size_t)b * N + g] = acc;
    }
}

extern "C" void kernel_launch(void* const* d_in, const int* in_sizes, int n_in,
                              void* d_out, int out_size, void* d_ws, size_t ws_size,
                              hipStream_t stream)
{
    (void)in_sizes; (void)n_in; (void)out_size;
    const float* x      = (const float*)d_in[0];
    const float* conv_w = (const float*)d_in[1];
    const float* conv_b = (const float*)d_in[2];
    const float* w_ih1  = (const float*)d_in[3];
    const float* w_hh1  = (const float*)d_in[4];
    const float* b1     = (const float*)d_in[5];
    const float* w_ih2  = (const float*)d_in[6];
    const float* w_hh2  = (const float*)d_in[7];
    const float* b2     = (const float*)d_in[8];
    const float* w_ih3  = (const float*)d_in[9];
    const float* w_hh3  = (const float*)d_in[10];
    const float* b3     = (const float*)d_in[11];
    const float* fc1_w  = (const float*)d_in[12];
    const float* fc1_b  = (const float*)d_in[13];
    const float* fc2_w  = (const float*)d_in[14];
    const float* fc2_b  = (const float*)d_in[15];
    const float* fc3_w  = (const float*)d_in[16];
    const float* fc3_b  = (const float*)d_in[17];
    const float* fc4_w  = (const float*)d_in[18];
    const float* fc4_b  = (const float*)d_in[19];
    float* out = (float*)d_out;
    char*  base = (char*)d_ws;

    const size_t MB = 1ull << 20;

    // footprint: 2 fp16 Y buffers + 2 fp16 XW chunk buffers (double-buffered) + small
    auto need = [&](int s, int tc) -> size_t {
        size_t Bg = B_ALL / s;
        size_t YB = Bg * T_SZ * 256 * 2;
        size_t XW = (size_t)tc * Bg * 512 * 2 * 2;       // fp16, 2 dirs
        return 2 * YB + 2 * XW + 2 * MB;
    };

    int S = 8;
    for (int s : {1, 2, 4, 8}) {
        if (need(s, 32) <= ws_size) { S = s; break; }
    }
    int Tc = 32;
    while (Tc < 256 && need(S, Tc * 2) <= ws_size) Tc <<= 1;
    int lg = 0; while ((1 << lg) < Tc) lg++;
    int NC = T_SZ / Tc;

    int Bg = B_ALL / S;
    size_t YB  = (size_t)Bg * T_SZ * 256 * 2;
    size_t XWB = (size_t)Tc * Bg * 512 * 2 * 2;
    _Float16* Y1 = (_Float16*)base;
    _Float16* Y2 = (_Float16*)(base + YB);
    _Float16* X1 = Y2;                                   // aliased: X1 dead before Y2 written
    _Float16* XW[2] = { (_Float16*)(base + 2 * YB), (_Float16*)(base + 2 * YB + XWB) };
    float* sm  = (float*)(base + 2 * YB + 2 * XWB);
    float* Hs = sm;                   // 2*Bg*128
    float* Cs = Hs + 2 * Bg * 128;
    float* H3 = Cs + 2 * Bg * 128;    // Bg*128
    float* F1 = H3 + Bg * 128;        // Bg*512
    float* F2 = F1 + Bg * 512;        // Bg*256
    float* F3 = F2 + Bg * 256;        // Bg*128

    int MT = Bg * Tc / 128;

    for (int sp = 0; sp < S; ++sp) {
        int bg0 = sp * Bg;

        conv_relu_kernel<<<dim3(T_SZ / 4, Bg), 256, 0, stream>>>(x, conv_w, conv_b, X1, bg0);

        // ---- layer 1 (K=64, N=512, H=128, 2 dirs): X1 -> Y1 ----
        {
            int NT = 4, ndir = 2, Kl = 64, Nn = 512;
            int nRec  = (Bg / 4) * ndir;
            int nProjB = 256 - nRec; if (nProjB < 64) nProjB = 64;
            int totT  = MT * NT * ndir;
            fused_step<128, true><<<256, 256, 0, stream>>>(
                XW[0], w_hh1, Y1, H3, Hs, Cs, Bg, Tc, lg, 0, 1, 0, 0, ndir,
                X1, w_ih1, b1, XW[0], Kl, Nn, 0, MT, NT, 256, totT);
            int par = 0;
            for (int ci = 0; ci < NC; ++ci) {
                int last = (ci == NC - 1);
                int grid = nRec + (last ? 0 : nProjB);
                fused_step<128, true><<<grid, 256, 0, stream>>>(
                    XW[par], w_hh1, Y1, H3, Hs, Cs, Bg, Tc, lg, ci * Tc, ci == 0, 0, nRec, ndir,
                    X1, w_ih1, b1, XW[1 - par], Kl, Nn, (ci + 1) * Tc, MT, NT, nProjB, totT);
                par ^= 1;
            }
        }
        // ---- layer 2 (K=256, N=512, H=128, 2 dirs): Y1 -> Y2 ----
        {
            int NT = 4, ndir = 2, Kl = 256, Nn = 512;
            int nRec  = (Bg / 4) * ndir;
            int nProjB = 256 - nRec; if (nProjB < 64) nProjB = 64;
            int totT  = MT * NT * ndir;
            fused_step<128, true><<<256, 256, 0, stream>>>(
                XW[0], w_hh2, Y2, H3, Hs, Cs, Bg, Tc, lg, 0, 1, 0, 0, ndir,
                Y1, w_ih2, b2, XW[0], Kl, Nn, 0, MT, NT, 256, totT);
            int par = 0;
            for (int ci = 0; ci < NC; ++ci) {
                int last = (ci == NC - 1);
                int grid = nRec + (last ? 0 : nProjB);
                fused_step<128, true><<<grid, 256, 0, stream>>>(
                    XW[par], w_hh2, Y2, H3, Hs, Cs, Bg, Tc, lg, ci * Tc, ci == 0, 0, nRec, ndir,
                    Y1, w_ih2, b2, XW[1 - par], Kl, Nn, (ci + 1) * Tc, MT, NT, nProjB, totT);
                par ^= 1;
            }
        }
        // ---- layer 3 fwd (K=256, N=256, H=64, 1 dir): Y2 -> H3[:,0:64] ----
        {
            int NT = 2, ndir = 1, Kl = 256, Nn = 256;
            int nRec  = (Bg / 4) * ndir;
            int nProjB = 256 - nRec; if (nProjB < 64) nProjB = 64;
            int totT  = MT * NT * ndir;
            fused_step<64, false><<<256, 256, 0, stream>>>(
                XW[0], w_hh3, nullptr, H3, Hs, Cs, Bg, Tc, lg, 0, 1, 0, 0, ndir,
                Y2, w_ih3, b3, XW[0], Kl, Nn, 0, MT, NT, 256, totT);
            int par = 0;
            for (int ci = 0; ci < NC; ++ci) {
                int last = (ci == NC - 1);
                int grid = nRec + (last ? 0 : nProjB);
                fused_step<64, false><<<grid, 256, 0, stream>>>(
                    XW[par], w_hh3, nullptr, H3, Hs, Cs, Bg, Tc, lg, ci * Tc, ci == 0, last, nRec, ndir,
                    Y2, w_ih3, b3, XW[1 - par], Kl, Nn, (ci + 1) * Tc, MT, NT, nProjB, totT);
                par ^= 1;
            }
        }
        lstm3_bwd_kernel<<<Bg, 256, 0, stream>>>(Y2, w_ih3, b3, H3);

        fc_kernel<<<Bg, 512, 128 * 4, stream>>>(H3, fc1_w, fc1_b, F1, 128, 512, 1);
        fc_kernel<<<Bg, 256, 512 * 4, stream>>>(F1, fc2_w, fc2_b, F2, 512, 256, 1);
        fc_kernel<<<Bg, 128, 256 * 4, stream>>>(F2, fc3_w, fc3_b, F3, 256, 128, 1);
        fc_kernel<<<Bg, 64, 128 * 4, stream>>>(F3, fc4_w, fc4_b, out + (size_t)bg0 * 2, 128, 2, 0);
    }
}

// Round 18
// 3561.229 us; speedup vs baseline: 1.0681x; 1.0681x over previous
//
#include <hip/hip_runtime.h>
#include <hip/hip_bf16.h>
#include <cstdint>
#include <cstddef>

#define B_ALL 256
#define T_SZ  1024

typedef __attribute__((ext_vector_type(8))) _Float16  halfx8;
typedef __attribute__((ext_vector_type(4))) _Float16  halfx4;
typedef __attribute__((ext_vector_type(4))) float     f32x4;

__device__ __forceinline__ float sig_(float x) {
    return __builtin_amdgcn_rcpf(1.0f + __expf(-x));
}
__device__ __forceinline__ float tanh_(float x) {
    float ax = fabsf(x);
    float e  = __expf(-2.0f * ax);
    float t  = (1.0f - e) * __builtin_amdgcn_rcpf(1.0f + e);
    return copysignf(t, x);
}

// LDS-only barrier (no vmcnt drain; vmem deps get compiler vmcnt waits at use).
__device__ __forceinline__ void bar_lgkm() {
    asm volatile("s_waitcnt lgkmcnt(0)\n\ts_barrier" ::: "memory");
}

// ---------------- conv (causal, k=5) + relu -> X1[b_local][t][64] (fp16) ----------------
__global__ void conv_relu_kernel(const float* __restrict__ x, const float* __restrict__ w,
                                 const float* __restrict__ bias, _Float16* __restrict__ out,
                                 int bg0)
{
    int c  = threadIdx.x & 63;
    int tq = threadIdx.x >> 6;
    int t  = blockIdx.x * 4 + tq;
    int b  = blockIdx.y;
    const float* xb = x + (size_t)(bg0 + b) * T_SZ;
    float s = bias[c];
#pragma unroll
    for (int k = 0; k < 5; ++k) {
        int ti = t - 4 + k;
        float xv = (ti >= 0) ? xb[ti] : 0.0f;
        s = fmaf(w[c * 5 + k], xv, s);
    }
    out[((size_t)b * T_SZ + t) * 64 + c] = (_Float16)fmaxf(s, 0.0f);
}

// ---------------- fused: LSTM rec (chunk ci) + input-proj MFMA (chunk ci+1) ----------------
// Rec blocks [0,nRecBlocks): 4 batch rows/block (1 h-unit per lane), XOR-swizzled h LDS
// (conflict-free b128), x4-unrolled step loop with scalar prefetch regs, MFMA chains
// split 2+2 to halve dependent depth. Proj blocks: persistent, grid-stride 128x128 tiles.
template <int H, int NW, bool WRITE_Y>
__global__ __launch_bounds__(512, 1) void fused_step(
    // rec
    const _Float16* __restrict__ xwR, const float* __restrict__ w_hh,
    _Float16* __restrict__ y, float* __restrict__ lastOut,
    float* __restrict__ Hst, float* __restrict__ Cst,
    int Bg, int Tc, int lg, int step0, int zeroInit, int writeLast,
    int nRecBlocks, int ndirRec,
    // proj
    const _Float16* __restrict__ A, const float* __restrict__ W,
    const float* __restrict__ bias, _Float16* __restrict__ xwOut,
    int K, int N, int t0p, int MT, int NT, int nProjB, int totTiles)
{
    __shared__ __align__(16) char smem[32768];
    const int tid = threadIdx.x;
    const int w   = tid >> 6;
    const int l   = tid & 63;
    const int l15 = l & 15;
    const int q4  = l >> 4;

    if ((int)blockIdx.x < nRecBlocks) {
        // ================= REC =================
        constexpr int FH  = 4 * H;
        constexpr int KT  = H / 32;
        constexpr int NCH = H / 8;          // 16B chunks per h row
        int rb  = blockIdx.x;
        int dir = (ndirRec == 2) ? (rb & 1) : 0;
        int bt  = (ndirRec == 2) ? (rb >> 1) : rb;
        int brow = bt * 4 + q4;             // this lane's batch row
        int hh   = w * 16 + l15;

        _Float16* hb = (_Float16*)smem;     // [parity][16 rows][NCH chunks] XOR-swizzled
        auto hAddr = [&](int p, int row, int ch) -> _Float16* {
            return hb + ((((p * 16 + row) * NCH) + (ch ^ (row & (NCH - 1)))) << 3);
        };
        for (int i = tid; i < 2 * 16 * H; i += 512) hb[i] = (_Float16)0.f;
        __syncthreads();                    // zero-init visible before h-init writes

        halfx8 wf[4][KT];
        float creg = 0.f;
        if (w < NW) {
            const float* wbase = w_hh + (size_t)dir * FH * H;
#pragma unroll
            for (int gate = 0; gate < 4; ++gate) {
                const float* wrow = wbase + (size_t)(gate * H + hh) * H;
#pragma unroll
                for (int kt = 0; kt < KT; ++kt) {
                    const float* src = wrow + kt * 32 + q4 * 8;
                    float4 a = *(const float4*)(src);
                    float4 b = *(const float4*)(src + 4);
                    halfx8 v;
                    v[0] = (_Float16)a.x; v[1] = (_Float16)a.y; v[2] = (_Float16)a.z; v[3] = (_Float16)a.w;
                    v[4] = (_Float16)b.x; v[5] = (_Float16)b.y; v[6] = (_Float16)b.z; v[7] = (_Float16)b.w;
                    wf[gate][kt] = v;
                }
            }
            float hv = 0.f;
            if (!zeroInit) {
                hv   = Hst[((size_t)dir * Bg + brow) * H + hh];
                creg = Cst[((size_t)dir * Bg + brow) * H + hh];
            }
            hAddr(0, q4 * 4, hh >> 3)[hh & 7] = (_Float16)hv;
        }
        const _Float16* xb = xwR + (size_t)dir * Tc * Bg * FH + (size_t)brow * FH + hh * 4;
        const size_t xstride = (size_t)Bg * FH;

        halfx4 pf0, pf1, pf2, pf3;
        if (w < NW) {
            pf0 = *(const halfx4*)(xb);
            pf1 = *(const halfx4*)(xb + xstride);
            pf2 = *(const halfx4*)(xb + 2 * xstride);
            pf3 = *(const halfx4*)(xb + 3 * xstride);
        }
        __syncthreads();

        // one sub-step: reads h from parity P, writes parity 1-P; all static indexing.
        // nx: pointer for the refill load (issued BEFORE the MFMA block), or null.
        auto step = [&](int sl, int P, halfx4 xv, const _Float16* nx, halfx4* pfd) {
            const int t = dir ? (T_SZ - 1 - (step0 + sl)) : (step0 + sl);
            if (nx) *pfd = *(const halfx4*)nx;   // refill early: load in flight during MFMA
            halfx8 af[KT];
#pragma unroll
            for (int kt = 0; kt < KT; ++kt)
                af[kt] = *(const halfx8*)hAddr(P, l15, kt * 4 + q4);
            float g4[4];
#pragma unroll
            for (int gate = 0; gate < 4; ++gate) {
                f32x4 a0 = {0.f, 0.f, 0.f, 0.f};
#pragma unroll
                for (int kt = 0; kt < KT / 2; ++kt)
                    a0 = __builtin_amdgcn_mfma_f32_16x16x32_f16(af[kt], wf[gate][kt], a0, 0, 0, 0);
                if (KT > 1) {
                    f32x4 a1 = {0.f, 0.f, 0.f, 0.f};
#pragma unroll
                    for (int kt = KT / 2; kt < KT; ++kt)
                        a1 = __builtin_amdgcn_mfma_f32_16x16x32_f16(af[kt], wf[gate][kt], a1, 0, 0, 0);
                    g4[gate] = a0[0] + a1[0] + (float)xv[gate];
                } else {
                    g4[gate] = a0[0] + (float)xv[gate];
                }
            }
            float iv = fminf(fmaxf(g4[0], -25.f), 25.f);
            float fv = fminf(fmaxf(g4[1], -25.f), 25.f);
            float gv = fminf(fmaxf(g4[2], -12.f), 12.f);
            float ov = fminf(fmaxf(g4[3], -25.f), 25.f);
            float Af = 1.f + __expf(-fv);
            float Bi = 1.f + __expf(-iv);
            float G  = __expf(2.f * gv);
            float Gp = G + 1.f, Gm = G - 1.f;
            float num = fmaf(creg * Bi, Gp, Af * Gm);
            float cn  = num * __builtin_amdgcn_rcpf(Af * Bi * Gp);
            creg = cn;
            float cc = fminf(fmaxf(cn, -25.f), 25.f);
            float E  = __expf(2.f * cc);
            float hv = (E - 1.f) * __builtin_amdgcn_rcpf((1.f + __expf(-ov)) * (E + 1.f));
            hAddr(1 - P, q4 * 4, hh >> 3)[hh & 7] = (_Float16)hv;
            if (WRITE_Y) {
                y[((size_t)brow * T_SZ + t) * (2 * H) + dir * H + hh] = (_Float16)hv;
            } else if (writeLast && sl == Tc - 1) {
                lastOut[brow * 128 + hh] = hv;
            }
            if (sl == Tc - 1) {
                Hst[((size_t)dir * Bg + brow) * H + hh] = hv;
                Cst[((size_t)dir * Bg + brow) * H + hh] = cn;
            }
        };

        for (int sl4 = 0; sl4 < Tc; sl4 += 4) {
            if (w < NW) {
                const _Float16* nx = (sl4 + 4 < Tc) ? (xb + (size_t)(sl4 + 4) * xstride) : nullptr;
                step(sl4 + 0, 0, pf0, nx, &pf0);
            }
            bar_lgkm();
            if (w < NW) {
                const _Float16* nx = (sl4 + 5 < Tc) ? (xb + (size_t)(sl4 + 5) * xstride) : nullptr;
                step(sl4 + 1, 1, pf1, nx, &pf1);
            }
            bar_lgkm();
            if (w < NW) {
                const _Float16* nx = (sl4 + 6 < Tc) ? (xb + (size_t)(sl4 + 6) * xstride) : nullptr;
                step(sl4 + 2, 0, pf2, nx, &pf2);
            }
            bar_lgkm();
            if (w < NW) {
                const _Float16* nx = (sl4 + 7 < Tc) ? (xb + (size_t)(sl4 + 7) * xstride) : nullptr;
                step(sl4 + 3, 1, pf3, nx, &pf3);
            }
            bar_lgkm();
        }
    } else {
        // ================= PROJ (persistent blocks, tile loop) =================
        const int Tcp = 1 << lg;
        const int H4  = N >> 2;
        int pb = blockIdx.x - nRecBlocks;

        for (int tile = pb; tile < totTiles; tile += nProjB) {
            int mi   = tile % MT;
            int rest = tile / MT;
            int ni   = rest % NT;
            int dirp = rest / NT;
            const float* Wd = W + (size_t)dirp * N * K;
            const float* bd = bias + (size_t)dirp * N;
            _Float16*    od = xwOut + (size_t)dirp * Tcp * Bg * N;

            _Float16 (*As)[40] = (_Float16(*)[40])smem;             // 128*40*2 = 10240
            _Float16 (*Ws)[40] = (_Float16(*)[40])(smem + 10240);   // 10240

            const int m0 = mi * 128;
            const int n0 = ni * 128;
            const int wm = (w & 1) * 64;
            const int wn = (w >> 1) * 32;

            f32x4 acc[4][2];
#pragma unroll
            for (int i = 0; i < 4; i++)
#pragma unroll
                for (int j = 0; j < 2; j++) acc[i][j] = (f32x4){0.f, 0.f, 0.f, 0.f};

            for (int k0 = 0; k0 < K; k0 += 32) {
                {   // stage A: 128 rows x 32 fp16, one pass of 512 x 16B
                    int row = tid >> 2;
                    int ko  = (tid & 3) * 8;
                    int m   = m0 + row;
                    int bA  = m >> lg, tl = m & (Tcp - 1);
                    int t   = dirp ? (T_SZ - 1 - (t0p + tl)) : (t0p + tl);
                    const _Float16* src = A + ((size_t)bA * T_SZ + t) * K + k0 + ko;
                    *(halfx8*)&As[row][ko] = *(const halfx8*)src;
                }
#pragma unroll
                for (int pass = 0; pass < 2; ++pass) {  // stage W: 128 rows x 32 f32->f16
                    int c2  = tid + pass * 512;
                    int row = c2 >> 3;
                    int ko  = (c2 & 7) * 4;
                    int n_o = n0 + row;
                    int nr  = (n_o & 3) * H4 + (n_o >> 2);
                    float4 f = *(const float4*)&Wd[(size_t)nr * K + k0 + ko];
                    halfx4 v;
                    v[0] = (_Float16)f.x; v[1] = (_Float16)f.y; v[2] = (_Float16)f.z; v[3] = (_Float16)f.w;
                    *(halfx4*)&Ws[row][ko] = v;
                }
                bar_lgkm();
                halfx8 af[4], bfr[2];
#pragma unroll
                for (int i = 0; i < 4; i++) af[i]  = *(const halfx8*)&As[wm + i * 16 + l15][q4 * 8];
#pragma unroll
                for (int j = 0; j < 2; j++) bfr[j] = *(const halfx8*)&Ws[wn + j * 16 + l15][q4 * 8];
#pragma unroll
                for (int i = 0; i < 4; i++)
#pragma unroll
                    for (int j = 0; j < 2; j++)
                        acc[i][j] = __builtin_amdgcn_mfma_f32_16x16x32_f16(af[i], bfr[j], acc[i][j], 0, 0, 0);
                bar_lgkm();
            }

            // epilogue: stage C in LDS [128][128] fp16, then coalesced 16B stores
            _Float16 (*Ct)[128] = (_Float16(*)[128])smem;
#pragma unroll
            for (int i = 0; i < 4; i++) {
#pragma unroll
                for (int j = 0; j < 2; j++) {
                    int o_l = wn + j * 16 + l15;
                    int n_o = n0 + o_l;
                    float bi = bd[(n_o & 3) * H4 + (n_o >> 2)];
#pragma unroll
                    for (int r = 0; r < 4; r++)
                        Ct[wm + i * 16 + q4 * 4 + r][o_l] = (_Float16)(acc[i][j][r] + bi);
                }
            }
            bar_lgkm();
            {
                int row = tid >> 2;          // 0..127
                int seg = tid & 3;           // 0..3, 32 fp16 each
                int m   = m0 + row;
                int bO  = m >> lg, tl = m & (Tcp - 1);
                _Float16* dst = od + ((size_t)tl * Bg + bO) * N + n0 + seg * 32;
                const _Float16* srcp = &Ct[row][seg * 32];
#pragma unroll
                for (int u = 0; u < 4; ++u)
                    *(halfx8*)(dst + u * 8) = *(const halfx8*)(srcp + u * 8);
            }
            bar_lgkm();   // Ct reads done before next tile's staging overwrites smem
        }
    }
}

// ---------------- layer-3 backward: exactly one step from zero state ----------------
__global__ __launch_bounds__(256) void lstm3_bwd_kernel(
    const _Float16* __restrict__ y2, const float* __restrict__ w_ih3,
    const float* __restrict__ b3, float* __restrict__ H3)
{
    int b = blockIdx.x, g = threadIdx.x;
    __shared__ float xr[256];
    __shared__ float gsh[256];
    xr[g] = (float)y2[((size_t)b * T_SZ + (T_SZ - 1)) * 256 + g];
    __syncthreads();
    const float* wr = w_ih3 + (size_t)256 * 256 + (size_t)g * 256;  // dir 1
    float acc = b3[256 + g];
#pragma unroll 4
    for (int k = 0; k < 256; k++) acc = fmaf(wr[k], xr[k], acc);
    gsh[g] = acc;
    __syncthreads();
    if (g < 64) {
        float iv = gsh[g], gv = gsh[128 + g], ov = gsh[192 + g];
        float ct = sig_(iv) * tanh_(gv);   // c0 = 0 -> forget term vanishes
        float hv = sig_(ov) * tanh_(ct);
        H3[b * 128 + 64 + g] = hv;
    }
}

// ---------------- FC ----------------
__global__ void fc_kernel(const float* __restrict__ in, const float* __restrict__ W,
                          const float* __restrict__ bias, float* __restrict__ out,
                          int K, int N, int doRelu)
{
    int b = blockIdx.x;
    int g = threadIdx.x;
    extern __shared__ float xr[];
    for (int i = g; i < K; i += blockDim.x) xr[i] = in[(size_t)b * K + i];
    __syncthreads();
    if (g < N) {
        const float* wr = W + (size_t)g * K;
        float acc = bias[g];
        for (int k = 0; k < K; k++) acc = fmaf(wr[k], xr[k], acc);
        if (doRelu) acc = fmaxf(acc, 0.f);
        out[(size_t)b * N + g] = acc;
    }
}

extern "C" void kernel_launch(void* const* d_in, const int* in_sizes, int n_in,
                              void* d_out, int out_size, void* d_ws, size_t ws_size,
                              hipStream_t stream)
{
    (void)in_sizes; (void)n_in; (void)out_size;
    const float* x      = (const float*)d_in[0];
    const float* conv_w = (const float*)d_in[1];
    const float* conv_b = (const float*)d_in[2];
    const float* w_ih1  = (const float*)d_in[3];
    const float* w_hh1  = (const float*)d_in[4];
    const float* b1     = (const float*)d_in[5];
    const float* w_ih2  = (const float*)d_in[6];
    const float* w_hh2  = (const float*)d_in[7];
    const float* b2     = (const float*)d_in[8];
    const float* w_ih3  = (const float*)d_in[9];
    const float* w_hh3  = (const float*)d_in[10];
    const float* b3     = (const float*)d_in[11];
    const float* fc1_w  = (const float*)d_in[12];
    const float* fc1_b  = (const float*)d_in[13];
    const float* fc2_w  = (const float*)d_in[14];
    const float* fc2_b  = (const float*)d_in[15];
    const float* fc3_w  = (const float*)d_in[16];
    const float* fc3_b  = (const float*)d_in[17];
    const float* fc4_w  = (const float*)d_in[18];
    const float* fc4_b  = (const float*)d_in[19];
    float* out = (float*)d_out;
    char*  base = (char*)d_ws;

    const size_t MB = 1ull << 20;

    // footprint: 2 fp16 Y buffers + 2 fp16 XW chunk buffers (double-buffered) + small
    auto need = [&](int s, int tc) -> size_t {
        size_t Bg = B_ALL / s;
        size_t YB = Bg * T_SZ * 256 * 2;
        size_t XW = (size_t)tc * Bg * 512 * 2 * 2;       // fp16, 2 dirs
        return 2 * YB + 2 * XW + 2 * MB;
    };

    int S = 8;
    for (int s : {1, 2, 4, 8}) {
        if (need(s, 32) <= ws_size) { S = s; break; }
    }
    int Tc = 32;
    while (Tc < 256 && need(S, Tc * 2) <= ws_size) Tc <<= 1;
    int lg = 0; while ((1 << lg) < Tc) lg++;
    int NC = T_SZ / Tc;

    int Bg = B_ALL / S;
    size_t YB  = (size_t)Bg * T_SZ * 256 * 2;
    size_t XWB = (size_t)Tc * Bg * 512 * 2 * 2;
    _Float16* Y1 = (_Float16*)base;
    _Float16* Y2 = (_Float16*)(base + YB);
    _Float16* X1 = Y2;                                   // aliased: X1 dead before Y2 written
    _Float16* XW[2] = { (_Float16*)(base + 2 * YB), (_Float16*)(base + 2 * YB + XWB) };
    float* sm  = (float*)(base + 2 * YB + 2 * XWB);
    float* Hs = sm;                   // 2*Bg*128
    float* Cs = Hs + 2 * Bg * 128;
    float* H3 = Cs + 2 * Bg * 128;    // Bg*128
    float* F1 = H3 + Bg * 128;        // Bg*512
    float* F2 = F1 + Bg * 512;        // Bg*256
    float* F3 = F2 + Bg * 256;        // Bg*128

    int MT = Bg * Tc / 128;

    for (int sp = 0; sp < S; ++sp) {
        int bg0 = sp * Bg;

        conv_relu_kernel<<<dim3(T_SZ / 4, Bg), 256, 0, stream>>>(x, conv_w, conv_b, X1, bg0);

        // ---- layer 1 (K=64, N=512, H=128, 2 dirs): X1 -> Y1 ----
        {
            int NT = 4, ndir = 2, Kl = 64, Nn = 512;
            int nRec  = (Bg / 4) * ndir;
            int nProjB = 256 - nRec; if (nProjB < 64) nProjB = 64;
            int totT  = MT * NT * ndir;
            fused_step<128, 8, true><<<256, 512, 0, stream>>>(
                XW[0], w_hh1, Y1, H3, Hs, Cs, Bg, Tc, lg, 0, 1, 0, 0, ndir,
                X1, w_ih1, b1, XW[0], Kl, Nn, 0, MT, NT, 256, totT);
            int par = 0;
            for (int ci = 0; ci < NC; ++ci) {
                int last = (ci == NC - 1);
                int grid = nRec + (last ? 0 : nProjB);
                fused_step<128, 8, true><<<grid, 512, 0, stream>>>(
                    XW[par], w_hh1, Y1, H3, Hs, Cs, Bg, Tc, lg, ci * Tc, ci == 0, 0, nRec, ndir,
                    X1, w_ih1, b1, XW[1 - par], Kl, Nn, (ci + 1) * Tc, MT, NT, nProjB, totT);
                par ^= 1;
            }
        }
        // ---- layer 2 (K=256, N=512, H=128, 2 dirs): Y1 -> Y2 ----
        {
            int NT = 4, ndir = 2, Kl = 256, Nn = 512;
            int nRec  = (Bg / 4) * ndir;
            int nProjB = 256 - nRec; if (nProjB < 64) nProjB = 64;
            int totT  = MT * NT * ndir;
            fused_step<128, 8, true><<<256, 512, 0, stream>>>(
                XW[0], w_hh2, Y2, H3, Hs, Cs, Bg, Tc, lg, 0, 1, 0, 0, ndir,
                Y1, w_ih2, b2, XW[0], Kl, Nn, 0, MT, NT, 256, totT);
            int par = 0;
            for (int ci = 0; ci < NC; ++ci) {
                int last = (ci == NC - 1);
                int grid = nRec + (last ? 0 : nProjB);
                fused_step<128, 8, true><<<grid, 512, 0, stream>>>(
                    XW[par], w_hh2, Y2, H3, Hs, Cs, Bg, Tc, lg, ci * Tc, ci == 0, 0, nRec, ndir,
                    Y1, w_ih2, b2, XW[1 - par], Kl, Nn, (ci + 1) * Tc, MT, NT, nProjB, totT);
                par ^= 1;
            }
        }
        // ---- layer 3 fwd (K=256, N=256, H=64, 1 dir): Y2 -> H3[:,0:64] ----
        {
            int NT = 2, ndir = 1, Kl = 256, Nn = 256;
            int nRec  = (Bg / 4) * ndir;
            int nProjB = 256 - nRec; if (nProjB < 64) nProjB = 64;
            int totT  = MT * NT * ndir;
            fused_step<64, 4, false><<<256, 512, 0, stream>>>(
                XW[0], w_hh3, nullptr, H3, Hs, Cs, Bg, Tc, lg, 0, 1, 0, 0, ndir,
                Y2, w_ih3, b3, XW[0], Kl, Nn, 0, MT, NT, 256, totT);
            int par = 0;
            for (int ci = 0; ci < NC; ++ci) {
                int last = (ci == NC - 1);
                int grid = nRec + (last ? 0 : nProjB);
                fused_step<64, 4, false><<<grid, 512, 0, stream>>>(
                    XW[par], w_hh3, nullptr, H3, Hs, Cs, Bg, Tc, lg, ci * Tc, ci == 0, last, nRec, ndir,
                    Y2, w_ih3, b3, XW[1 - par], Kl, Nn, (ci + 1) * Tc, MT, NT, nProjB, totT);
                par ^= 1;
            }
        }
        lstm3_bwd_kernel<<<Bg, 256, 0, stream>>>(Y2, w_ih3, b3, H3);

        fc_kernel<<<Bg, 512, 128 * 4, stream>>>(H3, fc1_w, fc1_b, F1, 128, 512, 1);
        fc_kernel<<<Bg, 256, 512 * 4, stream>>>(F1, fc2_w, fc2_b, F2, 512, 256, 1);
        fc_kernel<<<Bg, 128, 256 * 4, stream>>>(F2, fc3_w, fc3_b, F3, 256, 128, 1);
        fc_kernel<<<Bg, 64, 128 * 4, stream>>>(F3, fc4_w, fc4_b, out + (size_t)bg0 * 2, 128, 2, 0);
    }
}